// Round 1
// 148.484 us; speedup vs baseline: 1.0647x; 1.0647x over previous
//
#include <hip/hip_runtime.h>

typedef unsigned short ushort_t;
typedef __attribute__((ext_vector_type(8))) short short8;   // 8 bf16 payload (4 VGPRs)
typedef __attribute__((ext_vector_type(4))) float floatx4;  // MFMA C/D + epi math
typedef __attribute__((ext_vector_type(2))) float floatx2;

#define NN    32
#define CIN   128
#define COUT  256
#define NPTS  16384            // bs*v = 4*4096
#define NSAMP (NPTS * NN)      // 524288
#define LDA   136              // LDS A-tile stride (+16B pad)
#define HB    128              // histogram partial blocks (32 per batch)

// All scratch in .so-resident device globals. NO atomics anywhere -> every
// buffer is fully overwritten each run -> no zeroing kernel, no cross-run state.
__device__ __align__(16) ushort_t g_wb[COUT * CIN];            // 64 KB: W as bf16
__device__ __align__(16) ushort_t g_y[(size_t)NPTS * COUT];    // 8 MB: Y = fsp * W^T, bf16
__device__ __align__(16) int      g_hp[HB * 4096];             // 2 MB: per-chunk histograms
__device__ __align__(16) float    g_sp[256 * 512];             // 512 KB: per-block BN partials
__device__ __align__(16) float    g_consts[1536];              // scale,shift,d0,s0,s1,s2 per ch

__device__ __forceinline__ float bf2f(ushort_t u) {
    return __uint_as_float(((unsigned int)u) << 16);
}
__device__ __forceinline__ ushort_t f2bf(float f) {
    unsigned int x = __float_as_uint(f);
    return (ushort_t)((x + 0x7FFFu + ((x >> 16) & 1u)) >> 16);  // RNE
}
// Per-wave dtype probe: bf16 verts look plausible as bf16; f32 low halves don't.
__device__ __forceinline__ int probe_f32(const void* verts, int lane) {
    float ax = fabsf(bf2f(((const ushort_t*)verts)[lane]));
    unsigned long long b = __ballot((ax > 1e-5f) && (ax < 32.0f));
    return (__popcll(b) >= 56) ? 0 : 1;
}

// ---------------------------------------------------------------------------
// Kernel 1: atomic-free neighbor histogram partials + W -> bf16.
// Blocks [0,128): block b owns samples [b*4096,(b+1)*4096) -- all in batch
// b>>5 -- LDS-histograms them over the batch's 4096 vertices, stores partials.
// Blocks [128,160): convert W (32768 elems).
// ---------------------------------------------------------------------------
__global__ __launch_bounds__(256)
void hist_kernel(const int* __restrict__ nbr,
                 const void* __restrict__ Wg,
                 const void* __restrict__ verts) {
    __shared__ int h[4096];
    const int b   = blockIdx.x;
    const int tid = threadIdx.x;
    if (b < HB) {
        #pragma unroll
        for (int i = 0; i < 16; ++i) h[i * 256 + tid] = 0;
        __syncthreads();
        const int* src = nbr + (size_t)b * 4096;
        #pragma unroll
        for (int i = 0; i < 16; ++i) atomicAdd(&h[src[i * 256 + tid]], 1);  // LDS atomics only
        __syncthreads();
        int* dst = g_hp + (size_t)b * 4096;
        #pragma unroll
        for (int i = 0; i < 16; ++i) dst[i * 256 + tid] = h[i * 256 + tid];
    } else {
        const int f32 = probe_f32(verts, tid & 63);
        int i = (b - HB) * 1024 + tid * 4;
        if (f32) {
            float4 v = ((const float4*)Wg)[i >> 2];
            g_wb[i] = f2bf(v.x); g_wb[i + 1] = f2bf(v.y);
            g_wb[i + 2] = f2bf(v.z); g_wb[i + 3] = f2bf(v.w);
        } else {
            *(uint2*)(g_wb + i) = *(const uint2*)((const ushort_t*)Wg + i);
        }
    }
}

// ---------------------------------------------------------------------------
// Kernel 2: fused fsp-build + Y-GEMM + BN partial stats (no atomics).
// Stages 64 rows of [bf16(feat 0..126) ++ bf16(||row||)] straight from
// feature_map into LDS (kills the old g_fsp 8MB round trip + prep kernel),
// then M=64 x N=256 x K=128 MFMA GEMM; epilogue stores Y bf16 + per-block
// mult-weighted sum/sumsq partials to g_sp[block].
// ---------------------------------------------------------------------------
__global__ __launch_bounds__(256, 2)
void ygemm_kernel(const void* __restrict__ fm, const void* __restrict__ verts) {
    __shared__ __align__(16) ushort_t At[64 * LDA];
    __shared__ float multS[64];

    const int tid  = threadIdx.x;
    const int r0   = blockIdx.x * 64;
    const int lane = tid & 63;
    const int f32  = probe_f32(verts, lane);

    if (tid < 64) {   // multiplicity = sum of the batch's 32 histogram partials
        const int* hp = g_hp + (size_t)(r0 >> 12) * 32 * 4096 + (r0 & 4095) + tid;
        int s = 0;
        #pragma unroll
        for (int p2 = 0; p2 < 32; ++p2) s += hp[(size_t)p2 * 4096];
        multS[tid] = (float)s;
    }

    const int rl4 = tid >> 6;
    #pragma unroll 4
    for (int i = 0; i < 16; ++i) {
        const int rl = i * 4 + rl4;
        float f0, f1; ushort_t u0, u1;
        if (f32) {
            const float* src = (const float*)fm + (size_t)(r0 + rl) * 127;
            f0 = src[lane];
            f1 = (lane < 63) ? src[64 + lane] : 0.0f;
            u0 = f2bf(f0); u1 = f2bf(f1);
        } else {
            const ushort_t* src = (const ushort_t*)fm + (size_t)(r0 + rl) * 127;
            u0 = src[lane];
            u1 = (lane < 63) ? src[64 + lane] : (ushort_t)0;
            f0 = bf2f(u0); f1 = bf2f(u1);
        }
        float ss = f0 * f0 + f1 * f1;                 // fdist in fp32 (matches ref)
        #pragma unroll
        for (int d = 1; d < 64; d <<= 1) ss += __shfl_xor(ss, d, 64);
        At[rl * LDA + lane]      = u0;
        At[rl * LDA + 64 + lane] = (lane < 63) ? u1 : f2bf(sqrtf(ss));
    }
    __syncthreads();

    const int w = tid >> 6;              // wave -> channel strip w*64
    const int m = lane & 15;
    const int q = lane >> 4;

    floatx4 acc[4][4];
    #pragma unroll
    for (int rt = 0; rt < 4; ++rt)
        #pragma unroll
        for (int ct = 0; ct < 4; ++ct)
            acc[rt][ct] = (floatx4){0.0f, 0.0f, 0.0f, 0.0f};

    #pragma unroll
    for (int kk = 0; kk < 4; ++kk) {
        const int kof = kk * 32 + q * 8;
        short8 af[4];
        #pragma unroll
        for (int rt = 0; rt < 4; ++rt)
            af[rt] = *(const short8*)&At[(rt * 16 + m) * LDA + kof];
        short8 bfr[4];
        #pragma unroll
        for (int ct = 0; ct < 4; ++ct) {
            int ch = w * 64 + ct * 16 + m;
            bfr[ct] = *(const short8*)(g_wb + ch * CIN + kof);  // B[k][n]=W[n][k]
        }
        #pragma unroll
        for (int rt = 0; rt < 4; ++rt)
            #pragma unroll
            for (int ct = 0; ct < 4; ++ct)
                acc[rt][ct] = __builtin_amdgcn_mfma_f32_16x16x32_bf16(
                    af[rt], bfr[ct], acc[rt][ct], 0, 0, 0);
    }

    #pragma unroll
    for (int ct = 0; ct < 4; ++ct) {
        const int ch = w * 64 + ct * 16 + m;
        float s = 0.0f, ss = 0.0f;
        #pragma unroll
        for (int rt = 0; rt < 4; ++rt)
            #pragma unroll
            for (int j = 0; j < 4; ++j) {
                int rloc = rt * 16 + q * 4 + j;       // C/D: row=(lane>>4)*4+reg
                ushort_t yb = f2bf(acc[rt][ct][j]);
                g_y[(size_t)(r0 + rloc) * COUT + ch] = yb;
                float yv = bf2f(yb);                  // same value epi will read
                float wm = multS[rloc];
                s  += wm * yv;
                ss += wm * yv * yv;
            }
        s  += __shfl_xor(s, 16, 64);  s  += __shfl_xor(s, 32, 64);
        ss += __shfl_xor(ss, 16, 64); ss += __shfl_xor(ss, 32, 64);
        if (q == 0) {                                 // plain stores, no atomics
            g_sp[(size_t)blockIdx.x * 512 + ch]       = s;
            g_sp[(size_t)blockIdx.x * 512 + 256 + ch] = ss;
        }
    }
}

// ---------------------------------------------------------------------------
// Kernel 3: reduce the 256 BN partials + per-channel constants.
// bias b cancels exactly in train-mode BN (z - mean(z)) -> never read.
// ---------------------------------------------------------------------------
__global__ void finalize_kernel(const void* __restrict__ gamma,
                                const void* __restrict__ beta,
                                const void* __restrict__ dirs,
                                const void* __restrict__ verts) {
    const int c   = threadIdx.x;                      // 256 threads, 1 block
    const int f32 = probe_f32(verts, c & 63);

    float s = 0.0f, ss = 0.0f;
    #pragma unroll 8
    for (int p2 = 0; p2 < 256; ++p2) {
        s  += g_sp[(size_t)p2 * 512 + c];
        ss += g_sp[(size_t)p2 * 512 + 256 + c];
    }
    const float invN = 1.0f / (float)NSAMP;
    float mean = s * invN;
    float var  = fmaxf(ss * invN - mean * mean, 0.0f);  // biased
    float inv  = 1.0f / sqrtf(var + 1e-5f);
    float ga, be, d0, d1, d2, d3;
    if (f32) {
        ga = ((const float*)gamma)[c]; be = ((const float*)beta)[c];
        const float* dd = (const float*)dirs;
        d0 = dd[c]; d1 = dd[256 + c]; d2 = dd[512 + c]; d3 = dd[768 + c];
    } else {
        ga = bf2f(((const ushort_t*)gamma)[c]); be = bf2f(((const ushort_t*)beta)[c]);
        const ushort_t* dd = (const ushort_t*)dirs;
        d0 = bf2f(dd[c]); d1 = bf2f(dd[256 + c]);
        d2 = bf2f(dd[512 + c]); d3 = bf2f(dd[768 + c]);
    }
    float scale = ga * inv;
    g_consts[c]        = scale;
    g_consts[256 + c]  = be - mean * scale;
    g_consts[512 + c]  = d0;                          // directions[0]
    g_consts[768 + c]  = d1 - d0;                     // sup_w rows
    g_consts[1024 + c] = d2 - d0;
    g_consts[1280 + c] = d3 - d0;
}

// ---------------------------------------------------------------------------
// Kernel 4: epilogue. XCD-chunked swizzle: p = (bid&7)*2048 + bid>>3 puts
// each XCD on one contiguous 2048-point range (single batch -> 2MB g_y slice
// fits the 4MB per-XCD L2). Lane owns 4 channels -> dwordx2 gather = a full
// 512B row per wave-instruction; neighbors split across the 2 waves with an
// LDS max-combine; constants staged once per block through LDS.
// ---------------------------------------------------------------------------
__global__ __launch_bounds__(128, 4)
void epi_kernel(const int* __restrict__ nbr,
                const void* __restrict__ verts,
                void* __restrict__ out) {
    __shared__ int    rows[NN];
    __shared__ float4 dws[NN];
    __shared__ __align__(16) float cS[1536];
    __shared__ float4 xm1[64];

    const int tid  = threadIdx.x;
    const int bid  = blockIdx.x;
    const int p    = ((bid & 7) << 11) | (bid >> 3);   // XCD-chunked remap
    const int lane = tid & 63;
    const int f32  = probe_f32(verts, lane);

    #pragma unroll
    for (int k = 0; k < 3; ++k) {                      // stage 6KB consts
        int i4 = (k * 128 + tid) * 4;
        *(float4*)&cS[i4] = *(const float4*)&g_consts[i4];
    }
    if (tid < NN) {
        int gv = ((p >> 12) << 12) + nbr[p * NN + tid];
        rows[tid] = gv;
        float sx, sy, sz, nx, ny, nz;
        if (f32) {
            const float* vv = (const float*)verts;
            sx = vv[p * 3]; sy = vv[p * 3 + 1]; sz = vv[p * 3 + 2];
            nx = vv[gv * 3]; ny = vv[gv * 3 + 1]; nz = vv[gv * 3 + 2];
        } else {
            const ushort_t* vv = (const ushort_t*)verts;
            sx = bf2f(vv[p * 3]); sy = bf2f(vv[p * 3 + 1]); sz = bf2f(vv[p * 3 + 2]);
            nx = bf2f(vv[gv * 3]); ny = bf2f(vv[gv * 3 + 1]); nz = bf2f(vv[gv * 3 + 2]);
        }
        float dx = nx - sx, dy = ny - sy, dz = nz - sz;
        float nrm = sqrtf(dx * dx + dy * dy + dz * dz);
        float inv = 1.0f / fmaxf(nrm, 1e-12f);            // F.normalize eps
        dws[tid] = make_float4((dx * inv + 1.0f) * 0.5f,
                               (dy * inv + 1.0f) * 0.5f,
                               (dz * inv + 1.0f) * 0.5f, 0.0f);
    }
    __syncthreads();

    const int w  = tid >> 6;                           // wave -> neighbor half
    const int c4 = lane * 4;                           // 4 channels per lane
    const floatx4 zero = {0.0f, 0.0f, 0.0f, 0.0f};
    const floatx4 sc = *(const floatx4*)&cS[c4];
    const floatx4 sh = *(const floatx4*)&cS[256 + c4];
    const floatx4 d0 = *(const floatx4*)&cS[512 + c4];
    const floatx4 s0 = *(const floatx4*)&cS[768 + c4];
    const floatx4 s1 = *(const floatx4*)&cS[1024 + c4];
    const floatx4 s2 = *(const floatx4*)&cS[1280 + c4];

    floatx4 vm0 = zero, vm1 = zero, vm2 = zero, vm3 = zero;
    #pragma unroll
    for (int j0 = 0; j0 < 16; j0 += 4) {
        #pragma unroll
        for (int jj = 0; jj < 4; ++jj) {
            const int j = w * 16 + j0 + jj;
            int rb = __builtin_amdgcn_readfirstlane(rows[j]);   // SGPR row base
            const uint2 u = *(const uint2*)(g_y + (size_t)rb * COUT + c4);
            floatx4 y;
            y.x = __uint_as_float(u.x << 16);
            y.y = __uint_as_float(u.x & 0xFFFF0000u);
            y.z = __uint_as_float(u.y << 16);
            y.w = __uint_as_float(u.y & 0xFFFF0000u);
            float4 dw = dws[j];                        // ds_read_b128 broadcast
            floatx4 th = d0 + s0 * dw.x + s1 * dw.y + s2 * dw.z;
            th = __builtin_elementwise_max(th, zero);
            floatx4 zt = (y * sc + sh) * th;           // relu(z)*th == max(z*th,0)
            if      (jj == 0) vm0 = __builtin_elementwise_max(vm0, zt);
            else if (jj == 1) vm1 = __builtin_elementwise_max(vm1, zt);
            else if (jj == 2) vm2 = __builtin_elementwise_max(vm2, zt);
            else              vm3 = __builtin_elementwise_max(vm3, zt);
        }
    }
    floatx4 vm = __builtin_elementwise_max(
        __builtin_elementwise_max(vm0, vm1),
        __builtin_elementwise_max(vm2, vm3));          // accs >= 0 -> clamp built in

    if (w == 1) xm1[lane] = make_float4(vm.x, vm.y, vm.z, vm.w);
    __syncthreads();
    if (w == 0) {
        float4 o = xm1[lane];
        vm = __builtin_elementwise_max(vm, (floatx4){o.x, o.y, o.z, o.w});
        size_t ofs = (size_t)p * COUT + c4;
        if (f32) {
            *(floatx4*)((float*)out + ofs) = vm;
        } else {
            uint2 ou;
            ou.x = ((unsigned int)f2bf(vm.y) << 16) | (unsigned int)f2bf(vm.x);
            ou.y = ((unsigned int)f2bf(vm.w) << 16) | (unsigned int)f2bf(vm.z);
            *(uint2*)((ushort_t*)out + ofs) = ou;
        }
    }
}

// ---------------------------------------------------------------------------
extern "C" void kernel_launch(void* const* d_in, const int* in_sizes, int n_in,
                              void* d_out, int out_size, void* d_ws, size_t ws_size,
                              hipStream_t stream) {
    const int* nbr    = (const int*)d_in[0];
    const void* verts = d_in[1];
    const void* fm    = d_in[2];
    const void* dirs  = d_in[3];
    const void* Wg    = d_in[4];
    // d_in[5] = b: cancels exactly under train-mode BatchNorm -> unused
    const void* gamma = d_in[6];
    const void* beta  = d_in[7];
    (void)d_ws; (void)ws_size; (void)in_sizes; (void)n_in; (void)out_size;

    hist_kernel<<<dim3(HB + 32), dim3(256), 0, stream>>>(nbr, Wg, verts);
    ygemm_kernel<<<dim3(NPTS / 64), dim3(256), 0, stream>>>(fm, verts);
    finalize_kernel<<<dim3(1), dim3(256), 0, stream>>>(gamma, beta, dirs, verts);
    epi_kernel<<<dim3(NPTS), dim3(128), 0, stream>>>(nbr, verts, d_out);
}

// Round 3
// 139.064 us; speedup vs baseline: 1.1368x; 1.0677x over previous
//
#include <hip/hip_runtime.h>

typedef unsigned short ushort_t;
typedef __attribute__((ext_vector_type(8))) short short8;   // 8 bf16 payload (4 VGPRs)
typedef __attribute__((ext_vector_type(4))) float floatx4;  // MFMA C/D + epi math
typedef __attribute__((ext_vector_type(2))) float floatx2;

#define NN    32
#define CIN   128
#define COUT  256
#define NPTS  16384            // bs*v = 4*4096
#define NSAMP (NPTS * NN)      // 524288
#define LDA   136              // LDS A-tile stride (+16B pad)
#define HB    128              // histogram partial blocks (32 per batch)

// All scratch in .so-resident device globals. NO atomics anywhere -> every
// buffer is fully overwritten each run -> no zeroing kernel, no cross-run state.
__device__ __align__(16) ushort_t g_wb[COUT * CIN];            // 64 KB: W as bf16
__device__ __align__(16) ushort_t g_y[(size_t)NPTS * COUT];    // 8 MB: Y = fsp * W^T, bf16
__device__ __align__(16) int      g_hp[HB * 4096];             // 2 MB: per-chunk histograms
__device__ __align__(16) float    g_sp[256 * 512];             // 512 KB: per-block BN partials
__device__ __align__(16) float    g_consts[1536];              // scale,shift,d0,s0,s1,s2 per ch

__device__ __forceinline__ float bf2f(ushort_t u) {
    return __uint_as_float(((unsigned int)u) << 16);
}
__device__ __forceinline__ ushort_t f2bf(float f) {
    unsigned int x = __float_as_uint(f);
    return (ushort_t)((x + 0x7FFFu + ((x >> 16) & 1u)) >> 16);  // RNE
}
// Per-wave dtype probe: bf16 verts look plausible as bf16; f32 low halves don't.
__device__ __forceinline__ int probe_f32(const void* verts, int lane) {
    float ax = fabsf(bf2f(((const ushort_t*)verts)[lane]));
    unsigned long long b = __ballot((ax > 1e-5f) && (ax < 32.0f));
    return (__popcll(b) >= 56) ? 0 : 1;
}

// ---------------------------------------------------------------------------
// Kernel 1: atomic-free neighbor histogram partials + W -> bf16.
// Blocks [0,128): block b owns samples [b*4096,(b+1)*4096) -- all in batch
// b>>5 -- LDS-histograms them over the batch's 4096 vertices, stores partials.
// Blocks [128,160): convert W (32768 elems).
// ---------------------------------------------------------------------------
__global__ __launch_bounds__(256)
void hist_kernel(const int* __restrict__ nbr,
                 const void* __restrict__ Wg,
                 const void* __restrict__ verts) {
    __shared__ int h[4096];
    const int b   = blockIdx.x;
    const int tid = threadIdx.x;
    if (b < HB) {
        #pragma unroll
        for (int i = 0; i < 16; ++i) h[i * 256 + tid] = 0;
        __syncthreads();
        const int* src = nbr + (size_t)b * 4096;
        #pragma unroll
        for (int i = 0; i < 16; ++i) atomicAdd(&h[src[i * 256 + tid]], 1);  // LDS atomics only
        __syncthreads();
        int* dst = g_hp + (size_t)b * 4096;
        #pragma unroll
        for (int i = 0; i < 16; ++i) dst[i * 256 + tid] = h[i * 256 + tid];
    } else {
        const int f32 = probe_f32(verts, tid & 63);
        int i = (b - HB) * 1024 + tid * 4;
        if (f32) {
            float4 v = ((const float4*)Wg)[i >> 2];
            g_wb[i] = f2bf(v.x); g_wb[i + 1] = f2bf(v.y);
            g_wb[i + 2] = f2bf(v.z); g_wb[i + 3] = f2bf(v.w);
        } else {
            *(uint2*)(g_wb + i) = *(const uint2*)((const ushort_t*)Wg + i);
        }
    }
}

// ---------------------------------------------------------------------------
// Kernel 2: fused fsp-build + Y-GEMM + BN partial stats (no atomics).
// Stages 64 rows of [bf16(feat 0..126) ++ bf16(||row||)] straight from
// feature_map into LDS, then M=64 x N=256 x K=128 MFMA GEMM; epilogue stores
// Y bf16 + per-block mult-weighted sum/sumsq partials to g_sp[block].
// ---------------------------------------------------------------------------
__global__ __launch_bounds__(256, 2)
void ygemm_kernel(const void* __restrict__ fm, const void* __restrict__ verts) {
    __shared__ __align__(16) ushort_t At[64 * LDA];
    __shared__ float multS[64];

    const int tid  = threadIdx.x;
    const int r0   = blockIdx.x * 64;
    const int lane = tid & 63;
    const int f32  = probe_f32(verts, lane);

    if (tid < 64) {   // multiplicity = sum of the batch's 32 histogram partials
        const int* hp = g_hp + (size_t)(r0 >> 12) * 32 * 4096 + (r0 & 4095) + tid;
        int s = 0;
        #pragma unroll
        for (int p2 = 0; p2 < 32; ++p2) s += hp[(size_t)p2 * 4096];
        multS[tid] = (float)s;
    }

    const int rl4 = tid >> 6;
    #pragma unroll 4
    for (int i = 0; i < 16; ++i) {
        const int rl = i * 4 + rl4;
        float f0, f1; ushort_t u0, u1;
        if (f32) {
            const float* src = (const float*)fm + (size_t)(r0 + rl) * 127;
            f0 = src[lane];
            f1 = (lane < 63) ? src[64 + lane] : 0.0f;
            u0 = f2bf(f0); u1 = f2bf(f1);
        } else {
            const ushort_t* src = (const ushort_t*)fm + (size_t)(r0 + rl) * 127;
            u0 = src[lane];
            u1 = (lane < 63) ? src[64 + lane] : (ushort_t)0;
            f0 = bf2f(u0); f1 = bf2f(u1);
        }
        float ss = f0 * f0 + f1 * f1;                 // fdist in fp32 (matches ref)
        #pragma unroll
        for (int d = 1; d < 64; d <<= 1) ss += __shfl_xor(ss, d, 64);
        At[rl * LDA + lane]      = u0;
        At[rl * LDA + 64 + lane] = (lane < 63) ? u1 : f2bf(sqrtf(ss));
    }
    __syncthreads();

    const int w = tid >> 6;              // wave -> channel strip w*64
    const int m = lane & 15;
    const int q = lane >> 4;

    floatx4 acc[4][4];
    #pragma unroll
    for (int rt = 0; rt < 4; ++rt)
        #pragma unroll
        for (int ct = 0; ct < 4; ++ct)
            acc[rt][ct] = (floatx4){0.0f, 0.0f, 0.0f, 0.0f};

    #pragma unroll
    for (int kk = 0; kk < 4; ++kk) {
        const int kof = kk * 32 + q * 8;
        short8 af[4];
        #pragma unroll
        for (int rt = 0; rt < 4; ++rt)
            af[rt] = *(const short8*)&At[(rt * 16 + m) * LDA + kof];
        short8 bfr[4];
        #pragma unroll
        for (int ct = 0; ct < 4; ++ct) {
            int ch = w * 64 + ct * 16 + m;
            bfr[ct] = *(const short8*)(g_wb + ch * CIN + kof);  // B[k][n]=W[n][k]
        }
        #pragma unroll
        for (int rt = 0; rt < 4; ++rt)
            #pragma unroll
            for (int ct = 0; ct < 4; ++ct)
                acc[rt][ct] = __builtin_amdgcn_mfma_f32_16x16x32_bf16(
                    af[rt], bfr[ct], acc[rt][ct], 0, 0, 0);
    }

    #pragma unroll
    for (int ct = 0; ct < 4; ++ct) {
        const int ch = w * 64 + ct * 16 + m;
        float s = 0.0f, ss = 0.0f;
        #pragma unroll
        for (int rt = 0; rt < 4; ++rt)
            #pragma unroll
            for (int j = 0; j < 4; ++j) {
                int rloc = rt * 16 + q * 4 + j;       // C/D: row=(lane>>4)*4+reg
                ushort_t yb = f2bf(acc[rt][ct][j]);
                g_y[(size_t)(r0 + rloc) * COUT + ch] = yb;
                float yv = bf2f(yb);                  // same value epi will read
                float wm = multS[rloc];
                s  += wm * yv;
                ss += wm * yv * yv;
            }
        s  += __shfl_xor(s, 16, 64);  s  += __shfl_xor(s, 32, 64);
        ss += __shfl_xor(ss, 16, 64); ss += __shfl_xor(ss, 32, 64);
        if (q == 0) {                                 // plain stores, no atomics
            g_sp[(size_t)blockIdx.x * 512 + ch]       = s;
            g_sp[(size_t)blockIdx.x * 512 + 256 + ch] = ss;
        }
    }
}

// ---------------------------------------------------------------------------
// Kernel 3: reduce the 256 BN partials + per-channel constants.
// bias b cancels exactly in train-mode BN (z - mean(z)) -> never read.
// ---------------------------------------------------------------------------
__global__ void finalize_kernel(const void* __restrict__ gamma,
                                const void* __restrict__ beta,
                                const void* __restrict__ dirs,
                                const void* __restrict__ verts) {
    const int c   = threadIdx.x;                      // 256 threads, 1 block
    const int f32 = probe_f32(verts, c & 63);

    float s = 0.0f, ss = 0.0f;
    #pragma unroll 8
    for (int p2 = 0; p2 < 256; ++p2) {
        s  += g_sp[(size_t)p2 * 512 + c];
        ss += g_sp[(size_t)p2 * 512 + 256 + c];
    }
    const float invN = 1.0f / (float)NSAMP;
    float mean = s * invN;
    float var  = fmaxf(ss * invN - mean * mean, 0.0f);  // biased
    float inv  = 1.0f / sqrtf(var + 1e-5f);
    float ga, be, d0, d1, d2, d3;
    if (f32) {
        ga = ((const float*)gamma)[c]; be = ((const float*)beta)[c];
        const float* dd = (const float*)dirs;
        d0 = dd[c]; d1 = dd[256 + c]; d2 = dd[512 + c]; d3 = dd[768 + c];
    } else {
        ga = bf2f(((const ushort_t*)gamma)[c]); be = bf2f(((const ushort_t*)beta)[c]);
        const ushort_t* dd = (const ushort_t*)dirs;
        d0 = bf2f(dd[c]); d1 = bf2f(dd[256 + c]);
        d2 = bf2f(dd[512 + c]); d3 = bf2f(dd[768 + c]);
    }
    float scale = ga * inv;
    g_consts[c]        = scale;
    g_consts[256 + c]  = be - mean * scale;
    g_consts[512 + c]  = d0;                          // directions[0]
    g_consts[768 + c]  = d1 - d0;                     // sup_w rows
    g_consts[1024 + c] = d2 - d0;
    g_consts[1280 + c] = d3 - d0;
}

// ---------------------------------------------------------------------------
// Kernel 4: epilogue, half-wave-per-point. 256 thr / 4 waves / 8 points per
// block -> 2048 blocks (16x fewer dispatches). Lane owns 8 channels; one
// dwordx4 gather per neighbor covers the half-wave's full 512B g_y row.
// Setup uses ALL 64 lanes (one neighbor each, both points); row index packed
// into dws[].w so the main loop does a single ds_read_b128 per neighbor.
// One barrier, no cross-wave combine: each half-wave owns its point's full
// 32-neighbor max chain. XCD-chunked: blocks bid&7==k cover p in
// [k*2048,(k+1)*2048) -> per-XCD gather set = 2MB batch half-slice (< 4MB L2).
// ---------------------------------------------------------------------------
__global__ __launch_bounds__(256, 4)
void epi_kernel(const int* __restrict__ nbr,
                const void* __restrict__ verts,
                void* __restrict__ out) {
    __shared__ float4 dws[8][NN];                     // {wx,wy,wz, asfloat(row)}

    const int tid  = threadIdx.x;
    const int w    = tid >> 6;
    const int lane = tid & 63;
    const int h    = lane >> 5;                       // half-wave -> point
    const int j    = lane & 31;                       // neighbor owned in setup
    const int bid  = blockIdx.x;
    const int p0   = (((bid & 7) << 8) | (bid >> 3)) << 3;   // XCD-chunked, 8 pts
    const int p    = p0 + 2 * w + h;
    const int f32  = probe_f32(verts, lane);

    {   // setup: every lane computes one (point, neighbor) direction weight
        int gv = ((p >> 12) << 12) + nbr[(size_t)p * NN + j];
        float sx, sy, sz, nx, ny, nz;
        if (f32) {
            const float* vv = (const float*)verts;
            sx = vv[p * 3]; sy = vv[p * 3 + 1]; sz = vv[p * 3 + 2];
            nx = vv[gv * 3]; ny = vv[gv * 3 + 1]; nz = vv[gv * 3 + 2];
        } else {
            const ushort_t* vv = (const ushort_t*)verts;
            sx = bf2f(vv[p * 3]); sy = bf2f(vv[p * 3 + 1]); sz = bf2f(vv[p * 3 + 2]);
            nx = bf2f(vv[gv * 3]); ny = bf2f(vv[gv * 3 + 1]); nz = bf2f(vv[gv * 3 + 2]);
        }
        float dx = nx - sx, dy = ny - sy, dz = nz - sz;
        float nrm = sqrtf(dx * dx + dy * dy + dz * dz);
        float inv = 1.0f / fmaxf(nrm, 1e-12f);            // F.normalize eps
        dws[2 * w + h][j] = make_float4((dx * inv + 1.0f) * 0.5f,
                                        (dy * inv + 1.0f) * 0.5f,
                                        (dz * inv + 1.0f) * 0.5f,
                                        __int_as_float(gv));
    }
    __syncthreads();                                  // the only barrier

    const int cb = (lane & 31) * 8;                   // 8 channels per lane
    const floatx4 zero = {0.0f, 0.0f, 0.0f, 0.0f};
    const floatx4 scL = *(const floatx4*)&g_consts[cb];
    const floatx4 scH = *(const floatx4*)&g_consts[cb + 4];
    const floatx4 shL = *(const floatx4*)&g_consts[256 + cb];
    const floatx4 shH = *(const floatx4*)&g_consts[256 + cb + 4];
    const floatx4 d0L = *(const floatx4*)&g_consts[512 + cb];
    const floatx4 d0H = *(const floatx4*)&g_consts[512 + cb + 4];
    const floatx4 s0L = *(const floatx4*)&g_consts[768 + cb];
    const floatx4 s0H = *(const floatx4*)&g_consts[768 + cb + 4];
    const floatx4 s1L = *(const floatx4*)&g_consts[1024 + cb];
    const floatx4 s1H = *(const floatx4*)&g_consts[1024 + cb + 4];
    const floatx4 s2L = *(const floatx4*)&g_consts[1280 + cb];
    const floatx4 s2H = *(const floatx4*)&g_consts[1280 + cb + 4];

    const float4* dwp = dws[2 * w + h];
    floatx4 vmL0 = zero, vmH0 = zero, vmL1 = zero, vmH1 = zero;

    for (int j0 = 0; j0 < NN; j0 += 4) {
        float4 dw[4]; uint4 u[4];
        #pragma unroll
        for (int jj = 0; jj < 4; ++jj) {              // 4 gathers in flight
            dw[jj] = dwp[j0 + jj];                    // ds_read_b128 (bcast)
            int row = __float_as_int(dw[jj].w);
            u[jj] = *(const uint4*)(g_y + ((size_t)row << 8) + cb);
        }
        #pragma unroll
        for (int jj = 0; jj < 4; ++jj) {
            floatx4 yL, yH;
            yL.x = __uint_as_float(u[jj].x << 16);
            yL.y = __uint_as_float(u[jj].x & 0xFFFF0000u);
            yL.z = __uint_as_float(u[jj].y << 16);
            yL.w = __uint_as_float(u[jj].y & 0xFFFF0000u);
            yH.x = __uint_as_float(u[jj].z << 16);
            yH.y = __uint_as_float(u[jj].z & 0xFFFF0000u);
            yH.z = __uint_as_float(u[jj].w << 16);
            yH.w = __uint_as_float(u[jj].w & 0xFFFF0000u);
            floatx4 thL = d0L + s0L * dw[jj].x + s1L * dw[jj].y + s2L * dw[jj].z;
            floatx4 thH = d0H + s0H * dw[jj].x + s1H * dw[jj].y + s2H * dw[jj].z;
            thL = __builtin_elementwise_max(thL, zero);
            thH = __builtin_elementwise_max(thH, zero);
            floatx4 ztL = (yL * scL + shL) * thL;     // relu(z)*th == max(z*th,0)
            floatx4 ztH = (yH * scH + shH) * thH;
            if (jj & 1) {
                vmL1 = __builtin_elementwise_max(vmL1, ztL);
                vmH1 = __builtin_elementwise_max(vmH1, ztH);
            } else {
                vmL0 = __builtin_elementwise_max(vmL0, ztL);
                vmH0 = __builtin_elementwise_max(vmH0, ztH);
            }
        }
    }
    floatx4 vmL = __builtin_elementwise_max(vmL0, vmL1);   // accs >= 0
    floatx4 vmH = __builtin_elementwise_max(vmH0, vmH1);

    size_t ofs = (size_t)p * COUT + cb;
    if (f32) {
        *(floatx4*)((float*)out + ofs)     = vmL;
        *(floatx4*)((float*)out + ofs + 4) = vmH;
    } else {
        uint4 ou;
        ou.x = ((unsigned int)f2bf(vmL.y) << 16) | (unsigned int)f2bf(vmL.x);
        ou.y = ((unsigned int)f2bf(vmL.w) << 16) | (unsigned int)f2bf(vmL.z);
        ou.z = ((unsigned int)f2bf(vmH.y) << 16) | (unsigned int)f2bf(vmH.x);
        ou.w = ((unsigned int)f2bf(vmH.w) << 16) | (unsigned int)f2bf(vmH.z);
        *(uint4*)((ushort_t*)out + ofs) = ou;
    }
}

// ---------------------------------------------------------------------------
extern "C" void kernel_launch(void* const* d_in, const int* in_sizes, int n_in,
                              void* d_out, int out_size, void* d_ws, size_t ws_size,
                              hipStream_t stream) {
    const int* nbr    = (const int*)d_in[0];
    const void* verts = d_in[1];
    const void* fm    = d_in[2];
    const void* dirs  = d_in[3];
    const void* Wg    = d_in[4];
    // d_in[5] = b: cancels exactly under train-mode BatchNorm -> unused
    const void* gamma = d_in[6];
    const void* beta  = d_in[7];
    (void)d_ws; (void)ws_size; (void)in_sizes; (void)n_in; (void)out_size;

    hist_kernel<<<dim3(HB + 32), dim3(256), 0, stream>>>(nbr, Wg, verts);
    ygemm_kernel<<<dim3(NPTS / 64), dim3(256), 0, stream>>>(fm, verts);
    finalize_kernel<<<dim3(1), dim3(256), 0, stream>>>(gamma, beta, dirs, verts);
    epi_kernel<<<dim3(NPTS / 8), dim3(256), 0, stream>>>(nbr, verts, d_out);
}